// Round 8
// baseline (2377.868 us; speedup 1.0000x reference)
//
#include <hip/hip_runtime.h>

typedef __bf16 bf16x8 __attribute__((ext_vector_type(8)));
typedef float  f32x4  __attribute__((ext_vector_type(4)));
typedef unsigned short us4 __attribute__((ext_vector_type(4)));

#define N_CELLS 8000
#define N_GENES 8000
#define N_REG   20000
#define NF      100
#define KP      128     // padded K (factors) for MFMA
#define NFT     112     // padded factor count for ASr output (7*16)
#define KSPLIT  5       // split-K slices for ASr

static __device__ __forceinline__ unsigned short f2bf_bits(float f) {
  unsigned u = __builtin_bit_cast(unsigned, f);
  u = (u + 0x7FFFu + ((u >> 16) & 1u)) >> 16;   // RNE
  return (unsigned short)u;
}
static __device__ __forceinline__ __bf16 f2bf(float f) {
  unsigned short h = f2bf_bits(f);
  return __builtin_bit_cast(__bf16, h);
}
static __device__ __forceinline__ float bf2f(unsigned short s) {
  unsigned u = ((unsigned)s) << 16;
  return __builtin_bit_cast(float, u);
}
static __device__ __forceinline__ bf16x8 cvt8(f32x4 v0, f32x4 v1) {
  bf16x8 r;
  r[0]=f2bf(v0[0]); r[1]=f2bf(v0[1]); r[2]=f2bf(v0[2]); r[3]=f2bf(v0[3]);
  r[4]=f2bf(v1[0]); r[5]=f2bf(v1[1]); r[6]=f2bf(v1[2]); r[7]=f2bf(v1[3]);
  return r;
}

// ---------------- fused pre-pass (verbatim round-5/7)
__global__ __launch_bounds__(64) void pre_kernel(
    const float* __restrict__ C1, const float* __restrict__ C2,
    const float* __restrict__ Cg, const float* __restrict__ Cr,
    const float* __restrict__ Ag, const float* __restrict__ Ar,
    unsigned short* __restrict__ T1, unsigned short* __restrict__ T2,
    unsigned short* __restrict__ Sg, unsigned short* __restrict__ Sr,
    unsigned short* __restrict__ SrT,
    float* __restrict__ accv) {
  __shared__ float srow[NF];
  int b = blockIdx.x, t = threadIdx.x;
  if (b >= 44000) {            // loss3
    float d = 0.f, na = 0.f, nr = 0.f;
    for (int i = t; i < NF * NF; i += 64) {
      float a = Ag[i], r = Ar[i];
      d = fmaf(a, r, d); na = fmaf(a, a, na); nr = fmaf(r, r, nr);
    }
    #pragma unroll
    for (int off = 32; off > 0; off >>= 1) {
      d += __shfl_xor(d, off); na += __shfl_xor(na, off); nr += __shfl_xor(nr, off);
    }
    if (t == 0) { accv[2] = d; accv[3] = na; accv[4] = nr; }
    return;
  }
  const float* C; const float* W = nullptr;
  unsigned short* outR = nullptr; unsigned short* outT = nullptr;
  bool isSr = false;
  int i;
  if (b < 8000)       { C = C1; W = Ag; outT = T1; i = b; }
  else if (b < 16000) { C = C2; W = Ar; outT = T2; i = b - 8000; }
  else if (b < 24000) { C = Cg; outR = Sg; i = b - 16000; }
  else                { C = Cr; outR = Sr; isSr = true; i = b - 24000; }

  float v0 = C[i * NF + t];
  float v1 = (t < 36) ? C[i * NF + 64 + t] : -3.0e38f;
  float m = fmaxf(v0, v1);
  #pragma unroll
  for (int off = 32; off > 0; off >>= 1) m = fmaxf(m, __shfl_xor(m, off));
  float e0 = __expf(v0 - m);
  float e1 = (t < 36) ? __expf(v1 - m) : 0.f;
  float s = e0 + e1;
  #pragma unroll
  for (int off = 32; off > 0; off >>= 1) s += __shfl_xor(s, off);
  float inv = 1.f / s;
  e0 *= inv; e1 *= inv;

  if (outT == nullptr) {
    unsigned short b0 = f2bf_bits(e0);
    unsigned short b1 = (t < 36) ? f2bf_bits(e1) : (unsigned short)0;
    outR[i * KP + t] = b0;
    outR[i * KP + 64 + t] = b1;
    if (isSr) {
      SrT[t * N_REG + i] = b0;
      if (t < 48) SrT[(64 + t) * N_REG + i] = b1;
    }
    return;
  }
  srow[t] = e0;
  if (t < 36) srow[64 + t] = e1;
  __syncthreads();
  int c2 = 64 + t;
  int c2c = (c2 < NF) ? c2 : NF - 1;
  float a0=0.f, a1=0.f, a2=0.f, a3=0.f;
  float d0=0.f, d1=0.f, d2=0.f, d3=0.f;
  #pragma unroll 4
  for (int k = 0; k < NF; k += 4) {
    float s0 = srow[k], s1 = srow[k+1], s2 = srow[k+2], s3 = srow[k+3];
    a0 = fmaf(s0, W[(k  )*NF + t], a0);
    a1 = fmaf(s1, W[(k+1)*NF + t], a1);
    a2 = fmaf(s2, W[(k+2)*NF + t], a2);
    a3 = fmaf(s3, W[(k+3)*NF + t], a3);
    d0 = fmaf(s0, W[(k  )*NF + c2c], d0);
    d1 = fmaf(s1, W[(k+1)*NF + c2c], d1);
    d2 = fmaf(s2, W[(k+2)*NF + c2c], d2);
    d3 = fmaf(s3, W[(k+3)*NF + c2c], d3);
  }
  outT[i * KP + t]  = f2bf_bits((a0 + a1) + (a2 + a3));
  outT[i * KP + c2] = (c2 < NF) ? f2bf_bits((d0 + d1) + (d2 + d3)) : (unsigned short)0;
}

// ---------------- fused residual SSE (round-7 body; DIAG: nrep repeats, each
// rep's SSE scaled by invrep so totals are unchanged; X pointer laundered so
// reps genuinely re-stream from HBM)
__global__ __launch_bounds__(256, 3) void resid_kernel(
    const float* __restrict__ X,
    const unsigned short* __restrict__ Tm,
    const unsigned short* __restrict__ Sm,
    const float* __restrict__ bcol,
    const float* __restrict__ brow,
    int N, float* __restrict__ buckets, int nrep, float invrep) {
  __shared__ char ldsbuf[49152];
  char* ldsT = ldsbuf;
  char* ldsS = ldsbuf + 16384;
  int t = threadIdx.x;
  int wid = t >> 6, lane = t & 63;
  int lr = lane & 15, lg = lane >> 4;
  long r0blk = (long)blockIdx.y * 64;
  long c0blk = (long)blockIdx.x * 128;
  int r0 = (wid >> 1) * 32;
  int c0 = (wid & 1) * 64;

  for (int rep = 0; rep < nrep; ++rep) {
    const float* Xr = X;
    asm volatile("" : "+v"(Xr));   // block load-CSE across reps

    bf16x8 sT[4], sS[8];
    #pragma unroll
    for (int i2 = 0; i2 < 4; ++i2) {
      int g = i2 * 256 + t, row = g >> 4, gi = g & 15;
      sT[i2] = *reinterpret_cast<const bf16x8*>(Tm + (r0blk + row) * KP + gi * 8);
    }
    #pragma unroll
    for (int i2 = 0; i2 < 8; ++i2) {
      int g = i2 * 256 + t, row = g >> 4, gi = g & 15;
      sS[i2] = *reinterpret_cast<const bf16x8*>(Sm + (c0blk + row) * KP + gi * 8);
    }

    f32x4 xv[2][4];
    #pragma unroll
    for (int ri = 0; ri < 2; ++ri) {
      long row = r0blk + r0 + ri * 16 + lr;
      #pragma unroll
      for (int ci = 0; ci < 4; ++ci) {
        long cb = c0blk + c0 + ci * 16 + lg * 4;
        if (cb < N) xv[ri][ci] = *reinterpret_cast<const f32x4*>(Xr + row * N + cb);
        else        xv[ri][ci] = f32x4{0.f, 0.f, 0.f, 0.f};
      }
    }

    #pragma unroll
    for (int i2 = 0; i2 < 4; ++i2) {
      int g = i2 * 256 + t, row = g >> 4, gi = g & 15;
      int off = row * 256 + ((gi * 16) ^ ((row & 7) << 4));
      *reinterpret_cast<bf16x8*>(ldsT + off) = sT[i2];
    }
    #pragma unroll
    for (int i2 = 0; i2 < 8; ++i2) {
      int g = i2 * 256 + t, row = g >> 4, gi = g & 15;
      int off = row * 256 + ((gi * 16) ^ ((row & 7) << 4));
      *reinterpret_cast<bf16x8*>(ldsS + off) = sS[i2];
    }
    __syncthreads();

    f32x4 zero = {0.f, 0.f, 0.f, 0.f};
    f32x4 acc[4][2] = {{zero, zero}, {zero, zero}, {zero, zero}, {zero, zero}};
    #pragma unroll
    for (int ks = 0; ks < 4; ++ks) {
      bf16x8 a[4], bfr[2];
      #pragma unroll
      for (int ci = 0; ci < 4; ++ci) {
        int row = c0 + ci * 16 + lr;
        int off = row * 256 + (((ks * 64) + (lg * 16)) ^ ((row & 7) << 4));
        a[ci] = *reinterpret_cast<const bf16x8*>(ldsS + off);
      }
      #pragma unroll
      for (int ri = 0; ri < 2; ++ri) {
        int row = r0 + ri * 16 + lr;
        int off = row * 256 + (((ks * 64) + (lg * 16)) ^ ((row & 7) << 4));
        bfr[ri] = *reinterpret_cast<const bf16x8*>(ldsT + off);
      }
      #pragma unroll
      for (int ci = 0; ci < 4; ++ci)
        #pragma unroll
        for (int ri = 0; ri < 2; ++ri)
          acc[ci][ri] = __builtin_amdgcn_mfma_f32_16x16x32_bf16(a[ci], bfr[ri], acc[ci][ri], 0, 0, 0);
    }

    float brv[2];
    #pragma unroll
    for (int ri = 0; ri < 2; ++ri) brv[ri] = brow[r0blk + r0 + ri * 16 + lr];

    float sse = 0.f;
    #pragma unroll
    for (int ci = 0; ci < 4; ++ci) {
      long cb = c0blk + c0 + ci * 16 + lg * 4;
      if (cb < N) {
        f32x4 bc = *reinterpret_cast<const f32x4*>(bcol + cb);
        #pragma unroll
        for (int ri = 0; ri < 2; ++ri) {
          f32x4 x = xv[ri][ci];
          #pragma unroll
          for (int j = 0; j < 4; ++j) {
            float e = x[j] - acc[ci][ri][j] - bc[j] - brv[ri];
            sse = fmaf(e, e, sse);
          }
        }
      }
    }
    #pragma unroll
    for (int off = 32; off > 0; off >>= 1) sse += __shfl_xor(sse, off);
    sse *= invrep;
    __shared__ float wsum[4];
    if (lane == 0) wsum[wid] = sse;
    __syncthreads();
    if (t == 0)
      atomicAdd(&buckets[(blockIdx.y * gridDim.x + blockIdx.x) & 63],
                wsum[0] + wsum[1] + wsum[2] + wsum[3]);
  }
}

// ---------------- ASr (round-7 LDS-staged body; DIAG: nrep idempotent repeats)
__global__ __launch_bounds__(256) void asr_kernel(
    const float* __restrict__ A,
    const unsigned short* __restrict__ SrT,
    float* __restrict__ ASr5, int nrep) {
  __shared__ char lds[16384];
  int t = threadIdx.x;
  int w = t >> 6, lane = t & 63;
  int lr = lane & 15, lg = lane >> 4;
  int gBase = blockIdx.x * 64;
  int kb0 = blockIdx.y * (N_REG / KSPLIT);   // 4000

  const unsigned short* pb = SrT + (long)lr * N_REG + lg * 8;

  for (int rep = 0; rep < nrep; ++rep) {
    const float* Ar_ = A;
    asm volatile("" : "+v"(Ar_));   // block load-CSE across reps

    f32x4 zero = {0.f, 0.f, 0.f, 0.f};
    f32x4 acc[7] = {zero, zero, zero, zero, zero, zero, zero};

    #pragma unroll 1
    for (int it = 0; it < 32; ++it) {
      int kb = kb0 + it * 128;
      __syncthreads();
      if (it < 31) {
        #pragma unroll
        for (int p = 0; p < 4; ++p) {
          int flat = p * 2048 + t * 8;
          int row = flat >> 7, kk = flat & 127;
          const float* src = Ar_ + (long)(gBase + row) * N_REG + kb + kk;
          f32x4 v0 = *reinterpret_cast<const f32x4*>(src);
          f32x4 v1 = *reinterpret_cast<const f32x4*>(src + 4);
          int off = row * 256 + ((kk * 2) ^ ((row & 7) << 4));
          *reinterpret_cast<bf16x8*>(lds + off) = cvt8(v0, v1);
        }
      } else {
        int row = t >> 2, kk = (t & 3) * 8;
        const float* src = Ar_ + (long)(gBase + row) * N_REG + kb + kk;
        f32x4 v0 = *reinterpret_cast<const f32x4*>(src);
        f32x4 v1 = *reinterpret_cast<const f32x4*>(src + 4);
        int off = row * 256 + ((kk * 2) ^ ((row & 7) << 4));
        *reinterpret_cast<bf16x8*>(lds + off) = cvt8(v0, v1);
      }
      __syncthreads();
      int nk = (it < 31) ? 4 : 1;
      #pragma unroll 1
      for (int ks = 0; ks < nk; ++ks) {
        int row = w * 16 + lr;
        int off = row * 256 + (((ks * 64) + lg * 16) ^ ((row & 7) << 4));
        bf16x8 ag = *reinterpret_cast<const bf16x8*>(lds + off);
        #pragma unroll
        for (int ni = 0; ni < 7; ++ni) {
          bf16x8 b = *reinterpret_cast<const bf16x8*>(pb + (long)ni * 16 * N_REG + kb + ks * 32);
          acc[ni] = __builtin_amdgcn_mfma_f32_16x16x32_bf16(ag, b, acc[ni], 0, 0, 0);
        }
      }
    }

    float* slice = ASr5 + (long)blockIdx.y * (N_GENES * NFT);
    int g0 = gBase + w * 16;
    #pragma unroll
    for (int ni = 0; ni < 7; ++ni) {
      int f = ni * 16 + lr;
      #pragma unroll
      for (int j = 0; j < 4; ++j)
        slice[(g0 + lg * 4 + j) * NFT + f] = acc[ni][j];
    }
  }
}

// ---------------- loss4 pieces (verbatim round-5/7)
__global__ void l4red_kernel(const unsigned short* __restrict__ Sgbf,
                             const float* __restrict__ ASr5,
                             float* __restrict__ accv) {
  const int NV = N_GENES * NFT / 4;
  int t = blockIdx.x * blockDim.x + threadIdx.x;
  float d = 0.f, n1 = 0.f, n2 = 0.f;
  for (int q = t; q < NV; q += gridDim.x * blockDim.x) {
    int g = q / (NFT / 4);
    int f4 = (q - g * (NFT / 4)) * 4;
    f32x4 av = {0.f, 0.f, 0.f, 0.f};
    #pragma unroll
    for (int s = 0; s < KSPLIT; ++s)
      av += *reinterpret_cast<const f32x4*>(ASr5 + (long)s * (N_GENES * NFT) + g * NFT + f4);
    us4 sgb = *reinterpret_cast<const us4*>(Sgbf + g * KP + f4);
    #pragma unroll
    for (int j = 0; j < 4; ++j) {
      float sg = bf2f(sgb[j]);
      d = fmaf(sg, av[j], d); n1 = fmaf(sg, sg, n1); n2 = fmaf(av[j], av[j], n2);
    }
  }
  #pragma unroll
  for (int off = 32; off > 0; off >>= 1) {
    d += __shfl_xor(d, off); n1 += __shfl_xor(n1, off); n2 += __shfl_xor(n2, off);
  }
  __shared__ float r3[3][4];
  int lane = threadIdx.x & 63, w = threadIdx.x >> 6;
  if (lane == 0) { r3[0][w] = d; r3[1][w] = n1; r3[2][w] = n2; }
  __syncthreads();
  if (threadIdx.x == 0) {
    atomicAdd(&accv[5], r3[0][0] + r3[0][1] + r3[0][2] + r3[0][3]);
    atomicAdd(&accv[6], r3[1][0] + r3[1][1] + r3[1][2] + r3[1][3]);
    atomicAdd(&accv[7], r3[2][0] + r3[2][1] + r3[2][2] + r3[2][3]);
  }
}

// ---------------- finalize (verbatim round-5/7)
__global__ void fin_kernel(const float* __restrict__ accv,
                           const float* __restrict__ bk1,
                           const float* __restrict__ bk2,
                           const float* __restrict__ alpha,
                           float* __restrict__ out) {
  if (threadIdx.x == 0) {
    float s1 = 0.f, s2 = 0.f;
    for (int i = 0; i < 64; ++i) { s1 += bk1[i]; s2 += bk2[i]; }
    float loss1 = s1 / 64000000.0f;
    float loss2 = s2 / 160000000.0f;
    float loss3 = -accv[2] / (sqrtf(accv[3]) * sqrtf(accv[4]));
    float loss4 = -accv[5] / (sqrtf(accv[6]) * sqrtf(accv[7]));
    float l1 = alpha[0] * loss1, l2 = alpha[1] * loss2;
    float l3 = alpha[2] * loss3, l4 = alpha[3] * loss4;
    out[0] = l1 + l2 + l3 + l4;
    out[1] = l1; out[2] = l2; out[3] = l3; out[4] = l4;
  }
}

// ws layout: identical to round 5/7
//   0 accv[16] | 64 bk1[64] | 320 bk2[64] | 1024 ASr5 [5][8000][112] f32
//   17921024 T1 | 19969024 T2 | 22017024 Sg | 24065024 Sr | 29185024 SrT

extern "C" void kernel_launch(void* const* d_in, const int* in_sizes, int n_in,
                              void* d_out, int out_size, void* d_ws, size_t ws_size,
                              hipStream_t stream) {
  const float* G  = (const float*)d_in[0];
  const float* R  = (const float*)d_in[1];
  const float* A  = (const float*)d_in[2];
  const float* C1 = (const float*)d_in[3];
  const float* C2 = (const float*)d_in[4];
  const float* Cg = (const float*)d_in[5];
  const float* Cr = (const float*)d_in[6];
  const float* Ag = (const float*)d_in[7];
  const float* Ar = (const float*)d_in[8];
  const float* bg = (const float*)d_in[9];
  const float* br = (const float*)d_in[10];
  const float* b1 = (const float*)d_in[11];
  const float* b2 = (const float*)d_in[12];
  const float* alpha = (const float*)d_in[13];

  char* ws = (char*)d_ws;
  float* accv           = (float*)(ws + 0);
  float* buckets1       = (float*)(ws + 64);
  float* buckets2       = (float*)(ws + 320);
  float* ASr5           = (float*)(ws + 1024);
  unsigned short* T1    = (unsigned short*)(ws + 17921024);
  unsigned short* T2    = (unsigned short*)(ws + 19969024);
  unsigned short* Sg    = (unsigned short*)(ws + 22017024);
  unsigned short* Sr    = (unsigned short*)(ws + 24065024);
  unsigned short* SrT   = (unsigned short*)(ws + 29185024);

  hipMemsetAsync(d_ws, 0, 576, stream);

  pre_kernel<<<44001, 64, 0, stream>>>(C1, C2, Cg, Cr, Ag, Ar,
                                       T1, T2, Sg, Sr, SrT, accv);

  // DIAG repeats: G x8, R x4, asr x4 (results scaled/idempotent -> outputs unchanged)
  resid_kernel<<<dim3(63, 125), 256, 0, stream>>>(G, T1, Sg, bg, b1, N_GENES, buckets1,
                                                  8, 0.125f);
  resid_kernel<<<dim3(157, 125), 256, 0, stream>>>(R, T2, Sr, br, b2, N_REG, buckets2,
                                                   4, 0.25f);

  asr_kernel<<<dim3(125, KSPLIT), 256, 0, stream>>>(A, SrT, ASr5, 4);

  l4red_kernel<<<128, 256, 0, stream>>>(Sg, ASr5, accv);
  fin_kernel<<<1, 64, 0, stream>>>(accv, buckets1, buckets2, alpha, (float*)d_out);
}

// Round 9
// 650.495 us; speedup vs baseline: 3.6555x; 3.6555x over previous
//
#include <hip/hip_runtime.h>
#include <hip/hip_bf16.h>

typedef __bf16 bf16x8 __attribute__((ext_vector_type(8)));
typedef float  f32x4  __attribute__((ext_vector_type(4)));
typedef unsigned short us4 __attribute__((ext_vector_type(4)));

#define N_CELLS 8000
#define N_GENES 8000
#define N_REG   20000
#define NF      100
#define KP      128     // padded K (factors) for MFMA
#define NFT     112     // padded factor count for ASr output (7*16)
#define KSPLIT  25      // split-K slices for ASr (800 k = 25 k-steps each)

static __device__ __forceinline__ unsigned short f2bf_bits(float f) {
  unsigned u = __builtin_bit_cast(unsigned, f);
  u = (u + 0x7FFFu + ((u >> 16) & 1u)) >> 16;   // RNE
  return (unsigned short)u;
}
static __device__ __forceinline__ float bf2f(unsigned short s) {
  unsigned u = ((unsigned)s) << 16;
  return __builtin_bit_cast(float, u);
}
// native HW conversion (v_cvt) — used in asr's hot staging path
static __device__ __forceinline__ bf16x8 cvt8n(f32x4 v0, f32x4 v1) {
  bf16x8 r;
  r[0] = __builtin_bit_cast(__bf16, __float2bfloat16(v0[0]));
  r[1] = __builtin_bit_cast(__bf16, __float2bfloat16(v0[1]));
  r[2] = __builtin_bit_cast(__bf16, __float2bfloat16(v0[2]));
  r[3] = __builtin_bit_cast(__bf16, __float2bfloat16(v0[3]));
  r[4] = __builtin_bit_cast(__bf16, __float2bfloat16(v1[0]));
  r[5] = __builtin_bit_cast(__bf16, __float2bfloat16(v1[1]));
  r[6] = __builtin_bit_cast(__bf16, __float2bfloat16(v1[2]));
  r[7] = __builtin_bit_cast(__bf16, __float2bfloat16(v1[3]));
  return r;
}

// ---------------- fused pre-pass (verbatim round-5/7)
__global__ __launch_bounds__(64) void pre_kernel(
    const float* __restrict__ C1, const float* __restrict__ C2,
    const float* __restrict__ Cg, const float* __restrict__ Cr,
    const float* __restrict__ Ag, const float* __restrict__ Ar,
    unsigned short* __restrict__ T1, unsigned short* __restrict__ T2,
    unsigned short* __restrict__ Sg, unsigned short* __restrict__ Sr,
    unsigned short* __restrict__ SrT,
    float* __restrict__ accv) {
  __shared__ float srow[NF];
  int b = blockIdx.x, t = threadIdx.x;
  if (b >= 44000) {            // loss3
    float d = 0.f, na = 0.f, nr = 0.f;
    for (int i = t; i < NF * NF; i += 64) {
      float a = Ag[i], r = Ar[i];
      d = fmaf(a, r, d); na = fmaf(a, a, na); nr = fmaf(r, r, nr);
    }
    #pragma unroll
    for (int off = 32; off > 0; off >>= 1) {
      d += __shfl_xor(d, off); na += __shfl_xor(na, off); nr += __shfl_xor(nr, off);
    }
    if (t == 0) { accv[2] = d; accv[3] = na; accv[4] = nr; }
    return;
  }
  const float* C; const float* W = nullptr;
  unsigned short* outR = nullptr; unsigned short* outT = nullptr;
  bool isSr = false;
  int i;
  if (b < 8000)       { C = C1; W = Ag; outT = T1; i = b; }
  else if (b < 16000) { C = C2; W = Ar; outT = T2; i = b - 8000; }
  else if (b < 24000) { C = Cg; outR = Sg; i = b - 16000; }
  else                { C = Cr; outR = Sr; isSr = true; i = b - 24000; }

  float v0 = C[i * NF + t];
  float v1 = (t < 36) ? C[i * NF + 64 + t] : -3.0e38f;
  float m = fmaxf(v0, v1);
  #pragma unroll
  for (int off = 32; off > 0; off >>= 1) m = fmaxf(m, __shfl_xor(m, off));
  float e0 = __expf(v0 - m);
  float e1 = (t < 36) ? __expf(v1 - m) : 0.f;
  float s = e0 + e1;
  #pragma unroll
  for (int off = 32; off > 0; off >>= 1) s += __shfl_xor(s, off);
  float inv = 1.f / s;
  e0 *= inv; e1 *= inv;

  if (outT == nullptr) {
    unsigned short b0 = f2bf_bits(e0);
    unsigned short b1 = (t < 36) ? f2bf_bits(e1) : (unsigned short)0;
    outR[i * KP + t] = b0;
    outR[i * KP + 64 + t] = b1;
    if (isSr) {
      SrT[t * N_REG + i] = b0;
      if (t < 48) SrT[(64 + t) * N_REG + i] = b1;
    }
    return;
  }
  srow[t] = e0;
  if (t < 36) srow[64 + t] = e1;
  __syncthreads();
  int c2 = 64 + t;
  int c2c = (c2 < NF) ? c2 : NF - 1;
  float a0=0.f, a1=0.f, a2=0.f, a3=0.f;
  float d0=0.f, d1=0.f, d2=0.f, d3=0.f;
  #pragma unroll 4
  for (int k = 0; k < NF; k += 4) {
    float s0 = srow[k], s1 = srow[k+1], s2 = srow[k+2], s3 = srow[k+3];
    a0 = fmaf(s0, W[(k  )*NF + t], a0);
    a1 = fmaf(s1, W[(k+1)*NF + t], a1);
    a2 = fmaf(s2, W[(k+2)*NF + t], a2);
    a3 = fmaf(s3, W[(k+3)*NF + t], a3);
    d0 = fmaf(s0, W[(k  )*NF + c2c], d0);
    d1 = fmaf(s1, W[(k+1)*NF + c2c], d1);
    d2 = fmaf(s2, W[(k+2)*NF + c2c], d2);
    d3 = fmaf(s3, W[(k+3)*NF + c2c], d3);
  }
  outT[i * KP + t]  = f2bf_bits((a0 + a1) + (a2 + a3));
  outT[i * KP + c2] = (c2 < NF) ? f2bf_bits((d0 + d1) + (d2 + d3)) : (unsigned short)0;
}

// ---------------- fused residual SSE (verbatim round-7 production, no diag reps)
__global__ __launch_bounds__(256, 3) void resid_kernel(
    const float* __restrict__ X,
    const unsigned short* __restrict__ Tm,
    const unsigned short* __restrict__ Sm,
    const float* __restrict__ bcol,
    const float* __restrict__ brow,
    int N, float* __restrict__ buckets) {
  __shared__ char ldsbuf[49152];
  char* ldsT = ldsbuf;
  char* ldsS = ldsbuf + 16384;
  int t = threadIdx.x;
  int wid = t >> 6, lane = t & 63;
  int lr = lane & 15, lg = lane >> 4;
  long r0blk = (long)blockIdx.y * 64;
  long c0blk = (long)blockIdx.x * 128;
  int r0 = (wid >> 1) * 32;
  int c0 = (wid & 1) * 64;

  bf16x8 sT[4], sS[8];
  #pragma unroll
  for (int i2 = 0; i2 < 4; ++i2) {
    int g = i2 * 256 + t, row = g >> 4, gi = g & 15;
    sT[i2] = *reinterpret_cast<const bf16x8*>(Tm + (r0blk + row) * KP + gi * 8);
  }
  #pragma unroll
  for (int i2 = 0; i2 < 8; ++i2) {
    int g = i2 * 256 + t, row = g >> 4, gi = g & 15;
    sS[i2] = *reinterpret_cast<const bf16x8*>(Sm + (c0blk + row) * KP + gi * 8);
  }

  f32x4 xv[2][4];
  #pragma unroll
  for (int ri = 0; ri < 2; ++ri) {
    long row = r0blk + r0 + ri * 16 + lr;
    #pragma unroll
    for (int ci = 0; ci < 4; ++ci) {
      long cb = c0blk + c0 + ci * 16 + lg * 4;
      if (cb < N) xv[ri][ci] = *reinterpret_cast<const f32x4*>(X + row * N + cb);
      else        xv[ri][ci] = f32x4{0.f, 0.f, 0.f, 0.f};
    }
  }

  #pragma unroll
  for (int i2 = 0; i2 < 4; ++i2) {
    int g = i2 * 256 + t, row = g >> 4, gi = g & 15;
    int off = row * 256 + ((gi * 16) ^ ((row & 7) << 4));
    *reinterpret_cast<bf16x8*>(ldsT + off) = sT[i2];
  }
  #pragma unroll
  for (int i2 = 0; i2 < 8; ++i2) {
    int g = i2 * 256 + t, row = g >> 4, gi = g & 15;
    int off = row * 256 + ((gi * 16) ^ ((row & 7) << 4));
    *reinterpret_cast<bf16x8*>(ldsS + off) = sS[i2];
  }
  __syncthreads();

  f32x4 zero = {0.f, 0.f, 0.f, 0.f};
  f32x4 acc[4][2] = {{zero, zero}, {zero, zero}, {zero, zero}, {zero, zero}};
  #pragma unroll
  for (int ks = 0; ks < 4; ++ks) {
    bf16x8 a[4], bfr[2];
    #pragma unroll
    for (int ci = 0; ci < 4; ++ci) {
      int row = c0 + ci * 16 + lr;
      int off = row * 256 + (((ks * 64) + (lg * 16)) ^ ((row & 7) << 4));
      a[ci] = *reinterpret_cast<const bf16x8*>(ldsS + off);
    }
    #pragma unroll
    for (int ri = 0; ri < 2; ++ri) {
      int row = r0 + ri * 16 + lr;
      int off = row * 256 + (((ks * 64) + (lg * 16)) ^ ((row & 7) << 4));
      bfr[ri] = *reinterpret_cast<const bf16x8*>(ldsT + off);
    }
    #pragma unroll
    for (int ci = 0; ci < 4; ++ci)
      #pragma unroll
      for (int ri = 0; ri < 2; ++ri)
        acc[ci][ri] = __builtin_amdgcn_mfma_f32_16x16x32_bf16(a[ci], bfr[ri], acc[ci][ri], 0, 0, 0);
  }

  float brv[2];
  #pragma unroll
  for (int ri = 0; ri < 2; ++ri) brv[ri] = brow[r0blk + r0 + ri * 16 + lr];

  float sse = 0.f;
  #pragma unroll
  for (int ci = 0; ci < 4; ++ci) {
    long cb = c0blk + c0 + ci * 16 + lg * 4;
    if (cb < N) {
      f32x4 bc = *reinterpret_cast<const f32x4*>(bcol + cb);
      #pragma unroll
      for (int ri = 0; ri < 2; ++ri) {
        f32x4 x = xv[ri][ci];
        #pragma unroll
        for (int j = 0; j < 4; ++j) {
          float e = x[j] - acc[ci][ri][j] - bc[j] - brv[ri];
          sse = fmaf(e, e, sse);
        }
      }
    }
  }
  #pragma unroll
  for (int off = 32; off > 0; off >>= 1) sse += __shfl_xor(sse, off);
  __shared__ float wsum[4];
  if (lane == 0) wsum[wid] = sse;
  __syncthreads();
  if (t == 0)
    atomicAdd(&buckets[(blockIdx.y * gridDim.x + blockIdx.x) & 63],
              wsum[0] + wsum[1] + wsum[2] + wsum[3]);
}

// ---------------- ASr = A @ Sr — REWORKED: double-buffered LDS staging,
// one barrier per chunk, unrolled ks (28 L2 B-loads batch-issued), split-K 25.
// Block 256 thr = 4 waves, 64 genes x 112 factors, k-slice 800 = 6x128 + 32.
// Per chunk: [write staged regs -> buf] barrier [issue next chunk loads]
// [compute from buf] — HBM latency hides under MFMA + B-loads.
__global__ __launch_bounds__(256, 4) void asr_kernel(
    const float* __restrict__ A,
    const unsigned short* __restrict__ SrT,
    float* __restrict__ ASrN) {
  __shared__ char lds[2][16384];
  int t = threadIdx.x;
  int w = t >> 6, lane = t & 63;
  int lr = lane & 15, lg = lane >> 4;
  int gBase = blockIdx.x * 64;
  int kb0 = blockIdx.y * 800;

  const unsigned short* pb = SrT + (long)lr * N_REG + lg * 8;

  f32x4 zero = {0.f, 0.f, 0.f, 0.f};
  f32x4 acc[7] = {zero, zero, zero, zero, zero, zero, zero};
  f32x4 sreg[8];

  // prologue: load chunk 0 (128 k)
  #pragma unroll
  for (int p = 0; p < 4; ++p) {
    int flat = p * 2048 + t * 8;
    int row = flat >> 7, kk = flat & 127;
    const float* src = A + (long)(gBase + row) * N_REG + kb0 + kk;
    sreg[2 * p]     = *reinterpret_cast<const f32x4*>(src);
    sreg[2 * p + 1] = *reinterpret_cast<const f32x4*>(src + 4);
  }

  #pragma unroll 1
  for (int it = 0; it < 7; ++it) {
    // ---- write staged regs into buf[it&1]
    char* buf = lds[it & 1];
    if (it < 6) {
      #pragma unroll
      for (int p = 0; p < 4; ++p) {
        int flat = p * 2048 + t * 8;
        int row = flat >> 7, kk = flat & 127;
        int off = row * 256 + ((kk * 2) ^ ((row & 7) << 4));
        *reinterpret_cast<bf16x8*>(buf + off) = cvt8n(sreg[2 * p], sreg[2 * p + 1]);
      }
    } else {   // tail chunk: 32 k
      int row = t >> 2, kk = (t & 3) * 8;
      int off = row * 256 + ((kk * 2) ^ ((row & 7) << 4));
      *reinterpret_cast<bf16x8*>(buf + off) = cvt8n(sreg[0], sreg[1]);
    }
    __syncthreads();

    // ---- issue next chunk's global loads (in flight during compute)
    if (it < 5) {
      #pragma unroll
      for (int p = 0; p < 4; ++p) {
        int flat = p * 2048 + t * 8;
        int row = flat >> 7, kk = flat & 127;
        const float* src = A + (long)(gBase + row) * N_REG + kb0 + (it + 1) * 128 + kk;
        sreg[2 * p]     = *reinterpret_cast<const f32x4*>(src);
        sreg[2 * p + 1] = *reinterpret_cast<const f32x4*>(src + 4);
      }
    } else if (it == 5) {   // next is tail (32 k at kb0+768)
      int row = t >> 2, kk = (t & 3) * 8;
      const float* src = A + (long)(gBase + row) * N_REG + kb0 + 768 + kk;
      sreg[0] = *reinterpret_cast<const f32x4*>(src);
      sreg[1] = *reinterpret_cast<const f32x4*>(src + 4);
    }

    // ---- compute chunk it from buf (ks loop UNROLLED: B-loads batch)
    int kb = kb0 + it * 128;
    int arow = w * 16 + lr;
    int nk = (it < 6) ? 4 : 1;
    #pragma unroll 4
    for (int ks = 0; ks < nk; ++ks) {
      int off = arow * 256 + (((ks * 64) + lg * 16) ^ ((arow & 7) << 4));
      bf16x8 ag = *reinterpret_cast<const bf16x8*>(buf + off);
      #pragma unroll
      for (int ni = 0; ni < 7; ++ni) {
        bf16x8 b = *reinterpret_cast<const bf16x8*>(pb + (long)ni * 16 * N_REG + kb + ks * 32);
        acc[ni] = __builtin_amdgcn_mfma_f32_16x16x32_bf16(ag, b, acc[ni], 0, 0, 0);
      }
    }
  }

  // D: row(m=gene) = lg*4+j, col(n=factor) = ni*16+lr (mapping verified r5/r7)
  float* slice = ASrN + (long)blockIdx.y * (N_GENES * NFT);
  int g0 = gBase + w * 16;
  #pragma unroll
  for (int ni = 0; ni < 7; ++ni) {
    int f = ni * 16 + lr;
    #pragma unroll
    for (int j = 0; j < 4; ++j)
      slice[(g0 + lg * 4 + j) * NFT + f] = acc[ni][j];
  }
}

// ---------------- loss4 pieces (sums KSPLIT=25 slices)
__global__ void l4red_kernel(const unsigned short* __restrict__ Sgbf,
                             const float* __restrict__ ASrN,
                             float* __restrict__ accv) {
  const int NV = N_GENES * NFT / 4;
  int t = blockIdx.x * blockDim.x + threadIdx.x;
  float d = 0.f, n1 = 0.f, n2 = 0.f;
  for (int q = t; q < NV; q += gridDim.x * blockDim.x) {
    int g = q / (NFT / 4);
    int f4 = (q - g * (NFT / 4)) * 4;
    f32x4 av = {0.f, 0.f, 0.f, 0.f};
    #pragma unroll
    for (int s = 0; s < KSPLIT; ++s)
      av += *reinterpret_cast<const f32x4*>(ASrN + (long)s * (N_GENES * NFT) + g * NFT + f4);
    us4 sgb = *reinterpret_cast<const us4*>(Sgbf + g * KP + f4);
    #pragma unroll
    for (int j = 0; j < 4; ++j) {
      float sg = bf2f(sgb[j]);
      d = fmaf(sg, av[j], d); n1 = fmaf(sg, sg, n1); n2 = fmaf(av[j], av[j], n2);
    }
  }
  #pragma unroll
  for (int off = 32; off > 0; off >>= 1) {
    d += __shfl_xor(d, off); n1 += __shfl_xor(n1, off); n2 += __shfl_xor(n2, off);
  }
  __shared__ float r3[3][4];
  int lane = threadIdx.x & 63, w = threadIdx.x >> 6;
  if (lane == 0) { r3[0][w] = d; r3[1][w] = n1; r3[2][w] = n2; }
  __syncthreads();
  if (threadIdx.x == 0) {
    atomicAdd(&accv[5], r3[0][0] + r3[0][1] + r3[0][2] + r3[0][3]);
    atomicAdd(&accv[6], r3[1][0] + r3[1][1] + r3[1][2] + r3[1][3]);
    atomicAdd(&accv[7], r3[2][0] + r3[2][1] + r3[2][2] + r3[2][3]);
  }
}

// ---------------- finalize (verbatim round-5/7)
__global__ void fin_kernel(const float* __restrict__ accv,
                           const float* __restrict__ bk1,
                           const float* __restrict__ bk2,
                           const float* __restrict__ alpha,
                           float* __restrict__ out) {
  if (threadIdx.x == 0) {
    float s1 = 0.f, s2 = 0.f;
    for (int i = 0; i < 64; ++i) { s1 += bk1[i]; s2 += bk2[i]; }
    float loss1 = s1 / 64000000.0f;
    float loss2 = s2 / 160000000.0f;
    float loss3 = -accv[2] / (sqrtf(accv[3]) * sqrtf(accv[4]));
    float loss4 = -accv[5] / (sqrtf(accv[6]) * sqrtf(accv[7]));
    float l1 = alpha[0] * loss1, l2 = alpha[1] * loss2;
    float l3 = alpha[2] * loss3, l4 = alpha[3] * loss4;
    out[0] = l1 + l2 + l3 + l4;
    out[1] = l1; out[2] = l2; out[3] = l3; out[4] = l4;
  }
}

// ws layout (bytes):
//   0          : accv f32[16]                  (64)
//   64         : bk1 f32[64]                   (256)
//   320        : bk2 f32[64]                   (256)
//   1024       : ASrN f32 [25][8000][112]      (89,600,000)
//   89,601,024 : T1 bf16 [8000][128]           (2,048,000)
//   91,649,024 : T2 bf16 [8000][128]           (2,048,000)
//   93,697,024 : Sg bf16 [8000][128]           (2,048,000)
//   95,745,024 : Sr bf16 [20000][128]          (5,120,000)
//  100,865,024 : SrT bf16 [112][20000]         (4,480,000)  -> ~105 MB total

extern "C" void kernel_launch(void* const* d_in, const int* in_sizes, int n_in,
                              void* d_out, int out_size, void* d_ws, size_t ws_size,
                              hipStream_t stream) {
  const float* G  = (const float*)d_in[0];
  const float* R  = (const float*)d_in[1];
  const float* A  = (const float*)d_in[2];
  const float* C1 = (const float*)d_in[3];
  const float* C2 = (const float*)d_in[4];
  const float* Cg = (const float*)d_in[5];
  const float* Cr = (const float*)d_in[6];
  const float* Ag = (const float*)d_in[7];
  const float* Ar = (const float*)d_in[8];
  const float* bg = (const float*)d_in[9];
  const float* br = (const float*)d_in[10];
  const float* b1 = (const float*)d_in[11];
  const float* b2 = (const float*)d_in[12];
  const float* alpha = (const float*)d_in[13];

  char* ws = (char*)d_ws;
  float* accv           = (float*)(ws + 0);
  float* buckets1       = (float*)(ws + 64);
  float* buckets2       = (float*)(ws + 320);
  float* ASrN           = (float*)(ws + 1024);
  unsigned short* T1    = (unsigned short*)(ws + 89601024);
  unsigned short* T2    = (unsigned short*)(ws + 91649024);
  unsigned short* Sg    = (unsigned short*)(ws + 93697024);
  unsigned short* Sr    = (unsigned short*)(ws + 95745024);
  unsigned short* SrT   = (unsigned short*)(ws + 100865024);

  hipMemsetAsync(d_ws, 0, 576, stream);   // accv + buckets only (ASrN fully overwritten)

  pre_kernel<<<44001, 64, 0, stream>>>(C1, C2, Cg, Cr, Ag, Ar,
                                       T1, T2, Sg, Sr, SrT, accv);

  resid_kernel<<<dim3(63, 125), 256, 0, stream>>>(G, T1, Sg, bg, b1, N_GENES, buckets1);
  resid_kernel<<<dim3(157, 125), 256, 0, stream>>>(R, T2, Sr, br, b2, N_REG, buckets2);

  asr_kernel<<<dim3(125, KSPLIT), 256, 0, stream>>>(A, SrT, ASrN);

  l4red_kernel<<<128, 256, 0, stream>>>(Sg, ASrN, accv);
  fin_kernel<<<1, 64, 0, stream>>>(accv, buckets1, buckets2, alpha, (float*)d_out);
}